// Round 17
// baseline (133.902 us; speedup 1.0000x reference)
//
#include <hip/hip_runtime.h>

#define SEQ   2048
#define DIM   1024
#define NH    16
#define HD    64
#define BH    32          // BATCH*NH
#define TOK   4096        // BATCH*SEQ

typedef __bf16 bf16;
typedef __attribute__((ext_vector_type(4))) __bf16 bf16x4;
typedef __attribute__((ext_vector_type(8))) __bf16 bf16x8;
typedef __attribute__((ext_vector_type(4))) float f32x4;

#define LOG2E 1.44269504f

__device__ inline f32x4 mfma16(bf16x8 a, bf16x8 b, f32x4 c) {
  return __builtin_amdgcn_mfma_f32_16x16x32_bf16(a, b, c, 0, 0, 0);
}

__device__ inline void gload_lds16(const bf16* g, bf16* lds) {
  __builtin_amdgcn_global_load_lds(
      (const __attribute__((address_space(1))) void*)g,
      (__attribute__((address_space(3))) void*)lds, 16, 0, 0);
}

__device__ inline float exp2_hw(float x) {  // v_exp_f32: D = 2^S0
  float r;
  asm("v_exp_f32 %0, %1" : "=v"(r) : "v"(x));
  return r;
}

// split 8 consecutive f32 into bf16 hi + lo vectors
__device__ inline void split8(const float* src, bf16x8& hi, bf16x8& lo) {
  float4 a = *(const float4*)src;
  float4 b = *(const float4*)(src + 4);
  float f[8] = {a.x, a.y, a.z, a.w, b.x, b.y, b.z, b.w};
#pragma unroll
  for (int i = 0; i < 8; ++i) {
    bf16 h = (bf16)f[i];
    hi[i] = h;
    lo[i] = (bf16)(f[i] - (float)h);
  }
}

__device__ inline void cast8(const float* src, bf16* dst) {
  float4 a = *(const float4*)src;
  float4 b = *(const float4*)(src + 4);
  bf16x8 v;
  v[0] = (bf16)a.x; v[1] = (bf16)a.y; v[2] = (bf16)a.z; v[3] = (bf16)a.w;
  v[4] = (bf16)b.x; v[5] = (bf16)b.y; v[6] = (bf16)b.z; v[7] = (bf16)b.w;
  *(bf16x8*)dst = v;
}

// ---------------- fused prologue: x hi/lo split + w_qkv cast + out_w cast.
__global__ void prep_kernel(const float* __restrict__ x,
                            const float* __restrict__ kqv_w,
                            const float* __restrict__ out_w,
                            bf16* __restrict__ xh, bf16* __restrict__ xl,
                            bf16* __restrict__ wbf, bf16* __restrict__ wout) {
  const int NX8 = TOK * DIM / 8;
  const int NW8 = 3 * DIM * DIM / 8;
  const int NO8 = DIM * DIM / 8;
  int i = blockIdx.x * 256 + threadIdx.x;
  if (i < NX8) {
    bf16x8 h, l;
    split8(x + (size_t)i * 8, h, l);
    ((bf16x8*)xh)[i] = h;
    ((bf16x8*)xl)[i] = l;
  } else if (i < NX8 + NW8) {
    int j = i - NX8;
    cast8(kqv_w + (size_t)j * 8, wbf + (size_t)j * 8);
  } else if (i < NX8 + NW8 + NO8) {
    int j = i - NX8 - NW8;
    cast8(out_w + (size_t)j * 8, wout + (size_t)j * 8);
  }
}

// ---------------- QKV GEMM: xh * wh^T (+ xl * wh^T for Q panels only) + bias.
// 2-phase prefetch dbuf; XCD-swizzled 1D grid. Q's lo-operand (xl) is loaded
// DIRECTLY global->registers (wave-private fragments, L2-hot, latency hidden
// under the hi MFMA block) -- no Al LDS buffers (48->32 KB), fewer DS ops.
// V stored PRE-PERMUTED (vP): vP[n][kt][d][u], u = (p*4+l)*8 + h*4 + r
// for k = 32p+16h+4l+r  (kt = s>>6).
__global__ __launch_bounds__(256) void gemm_qkv_ps(
    const bf16* __restrict__ xh, const bf16* __restrict__ xl,
    const bf16* __restrict__ wbf, const float* __restrict__ bias,
    bf16* __restrict__ qhh, bf16* __restrict__ qhl, bf16* __restrict__ kh,
    bf16* __restrict__ vP) {
  __shared__ bf16 AhA[64 * 64], BhA[64 * 64];  // 16 KB
  __shared__ bf16 AhB[64 * 64], BhB[64 * 64];  // 16 KB
  const int tid = threadIdx.x;
  const int lane = tid & 63;
  const int wave = tid >> 6;
  const int lr = lane & 15, lk = lane >> 4;
  const int bid = blockIdx.x;
  const int swz = (bid & 7) * 96 + (bid >> 3);
  const int m0 = (swz / 24) * 128, n0 = (swz % 24) * 128;
  const bool two_term = (n0 < DIM);  // Q panels only: xl correction
  const int wm = (wave >> 1) * 64, wn = (wave & 1) * 64;
  f32x4 acc[4][4] = {};

  const int c0i = tid, c1i = 256 + tid;
  const int rp0 = c0i >> 3, lc0 = (c0i & 7) ^ (rp0 & 7);
  const int mm0 = (lc0 >> 2) * 64 + rp0, kk0 = (lc0 & 3) * 8;
  const int rp1 = c1i >> 3, lc1 = (c1i & 7) ^ (rp1 & 7);
  const int mm1 = (lc1 >> 2) * 64 + rp1, kk1 = (lc1 & 3) * 8;
  const bf16* pA0 = xh + (size_t)(m0 + mm0) * DIM + kk0;
  const bf16* pA1 = xh + (size_t)(m0 + mm1) * DIM + kk1;
  const bf16* pB0 = wbf + (size_t)(n0 + mm0) * DIM + kk0;
  const bf16* pB1 = wbf + (size_t)(n0 + mm1) * DIM + kk1;

  // per-lane direct-load pointers for the Q lo fragments (advance 32/step)
  const bf16* pXl[4];
#pragma unroll
  for (int i = 0; i < 4; ++i)
    pXl[i] = xl + (size_t)(m0 + wm + i * 16 + lr) * DIM + lk * 8;

  auto stageG = [&](bf16* Ah_, bf16* Bh_) {
    gload_lds16(pA0, Ah_ + c0i * 8);
    gload_lds16(pA1, Ah_ + c1i * 8);
    gload_lds16(pB0, Bh_ + c0i * 8);
    gload_lds16(pB1, Bh_ + c1i * 8);
    pA0 += 32; pA1 += 32;
    pB0 += 32; pB1 += 32;
  };

  auto computeG = [&](const bf16* Ah, const bf16* Bh) {
    bf16x8 afl[4];
    if (two_term) {
#pragma unroll
      for (int i = 0; i < 4; ++i) {
        afl[i] = *(const bf16x8*)pXl[i];   // global->reg, L2-hot
        pXl[i] += 32;
      }
    }
    bf16x8 afh[4], bfv[4];
#pragma unroll
    for (int i = 0; i < 4; ++i) {
      int m = wm + i * 16 + lr;
      int rp = m & 63;
      int pc = ((m >> 6) * 4 + lk) ^ (rp & 7);
      afh[i] = *(const bf16x8*)(Ah + rp * 64 + pc * 8);
    }
#pragma unroll
    for (int j = 0; j < 4; ++j) {
      int m = wn + j * 16 + lr;
      int rp = m & 63;
      int pc = ((m >> 6) * 4 + lk) ^ (rp & 7);
      bfv[j] = *(const bf16x8*)(Bh + rp * 64 + pc * 8);
    }
    __builtin_amdgcn_s_setprio(1);
#pragma unroll
    for (int i = 0; i < 4; ++i)
#pragma unroll
      for (int j = 0; j < 4; ++j)
        acc[i][j] = mfma16(afh[i], bfv[j], acc[i][j]);
    __builtin_amdgcn_s_setprio(0);
    if (two_term) {
      __builtin_amdgcn_s_setprio(1);
#pragma unroll
      for (int i = 0; i < 4; ++i)
#pragma unroll
        for (int j = 0; j < 4; ++j)
          acc[i][j] = mfma16(afl[i], bfv[j], acc[i][j]);
      __builtin_amdgcn_s_setprio(0);
    }
  };

  stageG(AhA, BhA);  // K-step 0
  __syncthreads();
  for (int k0 = 0; k0 < DIM; k0 += 64) {
    stageG(AhB, BhB);              // prefetch step t+1
    computeG(AhA, BhA);            // step t
    __syncthreads();
    if (k0 + 64 < DIM) {
      stageG(AhA, BhA);            // prefetch step t+2
    }
    computeG(AhB, BhB);            // step t+1
    __syncthreads();
  }

  // D frag: row = lk*4 + r, col = lr
#pragma unroll
  for (int j = 0; j < 4; ++j) {
    int col = n0 + wn + j * 16 + lr;
    float bv = bias[col];
    int part = col >> 10, cc2 = col & 1023;
    int h = cc2 >> 6, d = cc2 & 63;
#pragma unroll
    for (int i = 0; i < 4; ++i) {
      int rowb = m0 + wm + i * 16 + lk * 4;
#pragma unroll
      for (int r = 0; r < 4; ++r) {
        int row = rowb + r;
        float val = acc[i][j][r] + bv;
        int b = row >> 11, s = row & 2047;
        int n = b * NH + h;
        size_t idx = ((size_t)n * SEQ + s) * HD + d;
        if (part == 0) {
          float vq = val * LOG2E;      // log2-domain fold
          bf16 qh_ = (bf16)vq;
          qhh[idx] = qh_;
          qhl[idx] = (bf16)(vq - (float)qh_);
        } else if (part == 1) {
          kh[idx] = (bf16)val;
        } else {
          // pre-permuted V: k = s -> (kt, p, hh, l, rr); u = (p*4+l)*8 + hh*4 + rr
          int kt = s >> 6;
          int s6 = s & 63;
          int p = (s6 >> 5) & 1;
          int s5 = s6 & 31;
          int hh = s5 >> 4, l = (s5 >> 2) & 3, rr = s5 & 3;
          int u = (p * 4 + l) * 8 + hh * 4 + rr;
          vP[(((size_t)n * 32 + kt) * 64 + d) * 64 + u] = (bf16)val;
        }
      }
    }
  }
}

// ---------------- output projection: C = A * Bw^T + bias, bf16 in, f32 out.
__global__ __launch_bounds__(256) void gemm_out(
    const bf16* __restrict__ A, const bf16* __restrict__ Bw,
    const float* __restrict__ bias, float* __restrict__ outF) {
  __shared__ bf16 AsA[64 * 64], BsA[64 * 64];
  __shared__ bf16 AsB[64 * 64], BsB[64 * 64];
  const int tid = threadIdx.x;
  const int lane = tid & 63;
  const int wave = tid >> 6;
  const int lr = lane & 15, lk = lane >> 4;
  const int bid = blockIdx.x;
  const int swz = (bid & 7) * 32 + (bid >> 3);
  const int m0 = (swz >> 3) * 128, n0 = (swz & 7) * 128;
  const int wm = (wave >> 1) * 64, wn = (wave & 1) * 64;
  f32x4 acc[4][4] = {};

  const int c0i = tid, c1i = 256 + tid;
  const int rp0 = c0i >> 3, lc0 = (c0i & 7) ^ (rp0 & 7);
  const int mm0 = (lc0 >> 2) * 64 + rp0, kk0 = (lc0 & 3) * 8;
  const int rp1 = c1i >> 3, lc1 = (c1i & 7) ^ (rp1 & 7);
  const int mm1 = (lc1 >> 2) * 64 + rp1, kk1 = (lc1 & 3) * 8;
  const bf16* pA0 = A + (size_t)(m0 + mm0) * DIM + kk0;
  const bf16* pA1 = A + (size_t)(m0 + mm1) * DIM + kk1;
  const bf16* pB0 = Bw + (size_t)(n0 + mm0) * DIM + kk0;
  const bf16* pB1 = Bw + (size_t)(n0 + mm1) * DIM + kk1;

#define STAGEO(As_, Bs_)              \
  do {                                \
    gload_lds16(pA0, As_ + c0i * 8);  \
    gload_lds16(pA1, As_ + c1i * 8);  \
    gload_lds16(pB0, Bs_ + c0i * 8);  \
    gload_lds16(pB1, Bs_ + c1i * 8);  \
    pA0 += 32; pA1 += 32;             \
    pB0 += 32; pB1 += 32;             \
  } while (0)

  auto computeO = [&](const bf16* As, const bf16* Bs) {
    bf16x8 af[4], bfv[4];
#pragma unroll
    for (int i = 0; i < 4; ++i) {
      int m = wm + i * 16 + lr;
      int rp = m & 63;
      int pc = ((m >> 6) * 4 + lk) ^ (rp & 7);
      af[i] = *(const bf16x8*)(As + rp * 64 + pc * 8);
    }
#pragma unroll
    for (int j = 0; j < 4; ++j) {
      int m = wn + j * 16 + lr;
      int rp = m & 63;
      int pc = ((m >> 6) * 4 + lk) ^ (rp & 7);
      bfv[j] = *(const bf16x8*)(Bs + rp * 64 + pc * 8);
    }
    __builtin_amdgcn_s_setprio(1);
#pragma unroll
    for (int i = 0; i < 4; ++i)
#pragma unroll
      for (int j = 0; j < 4; ++j)
        acc[i][j] = mfma16(af[i], bfv[j], acc[i][j]);
    __builtin_amdgcn_s_setprio(0);
  };

  STAGEO(AsA, BsA);
  __syncthreads();
  for (int k0 = 0; k0 < DIM; k0 += 64) {
    STAGEO(AsB, BsB);
    computeO(AsA, BsA);
    __syncthreads();
    if (k0 + 64 < DIM) {
      STAGEO(AsA, BsA);
    }
    computeO(AsB, BsB);
    __syncthreads();
  }
#undef STAGEO

#pragma unroll
  for (int j = 0; j < 4; ++j) {
    int col = n0 + wn + j * 16 + lr;
    float bv = bias[col];
#pragma unroll
    for (int i = 0; i < 4; ++i) {
      int rowb = m0 + wm + i * 16 + lk * 4;
#pragma unroll
      for (int r = 0; r < 4; ++r)
        outF[(size_t)(rowb + r) * DIM + col] = acc[i][j][r] + bv;
    }
  }
}

// ---------------- flash attention: intra-block KV-split (8 waves = 2 groups of
// 4), 32 q-rows/wave, swapped QK^T, in-register P, no max tracking. Group G
// processes KV-half G (16 tiles); since P = 2^s with no max, partials combine
// by pure f32 ADDITION through LDS at block end. 16 waves/CU.
__global__ __launch_bounds__(512) void attn_kernel(
    const bf16* __restrict__ qhh, const bf16* __restrict__ qhl,
    const bf16* __restrict__ kh, const bf16* __restrict__ vP,
    bf16* __restrict__ aout) {
  __shared__ bf16 smem[8 * 4096];  // 8 tiles x 8 KB = 64 KB; reused for combine
  const int tid = threadIdx.x;
  const int lane = tid & 63;
  const int w = tid >> 6;          // 0..7
  const int G = w >> 2;            // KV half
  const int wsub = w & 3;
  const int lr = lane & 15, lk = lane >> 4;
  const int bid = blockIdx.x;
  const int swz = (bid & 7) * 64 + (bid >> 3);
  const int n = swz >> 4;                        // head index
  const int q0 = (swz & 15) * 128 + wsub * 32;   // 32 q-rows per wave
  const int kv0 = G * (SEQ / 2);                 // this group's KV base

  // tile pointers: [buf A/B][group][K/V], 4096 elems (8 KB) each
  bf16* KsA = smem + ((0 * 2 + G) * 2 + 0) * 4096;
  bf16* VsA = smem + ((0 * 2 + G) * 2 + 1) * 4096;
  bf16* KsB = smem + ((1 * 2 + G) * 2 + 0) * 4096;
  bf16* VsB = smem + ((1 * 2 + G) * 2 + 1) * 4096;

  const bf16* qbh = qhh + ((size_t)n * SEQ + q0) * HD;
  const bf16* qbl = qhl + ((size_t)n * SEQ + q0) * HD;
  bf16x8 aqh[2][2], aql[2][2];
#pragma unroll
  for (int g = 0; g < 2; ++g) {
    aqh[g][0] = *(const bf16x8*)(qbh + (g * 16 + lr) * HD + lk * 8);
    aqh[g][1] = *(const bf16x8*)(qbh + (g * 16 + lr) * HD + 32 + lk * 8);
    aql[g][0] = *(const bf16x8*)(qbl + (g * 16 + lr) * HD + lk * 8);
    aql[g][1] = *(const bf16x8*)(qbl + (g * 16 + lr) * HD + 32 + lk * 8);
  }

  // staging: group-local thread gtid handles chunks gtid and 256+gtid;
  // chunk c -> LDS row rp=c>>3, logical chunk lc=(c&7)^(rp&7)  (both K and V)
  const int gtid = tid & 255;
  const int c0i = gtid, c1i = 256 + gtid;
  const int r0 = c0i >> 3, lc0 = ((c0i & 7) ^ (r0 & 7)) * 8;
  const int r1 = c1i >> 3, lc1 = ((c1i & 7) ^ (r1 & 7)) * 8;
  const size_t kbase = (size_t)n * SEQ * HD;
  const bf16* pK0 = kh + kbase + (size_t)(kv0 + r0) * HD + lc0;
  const bf16* pK1 = kh + kbase + (size_t)(kv0 + r1) * HD + lc1;
  const bf16* pV0 = vP + kbase + (size_t)(kv0 + r0) * 64 + lc0;  // vP tile: [64 d][64 u]
  const bf16* pV1 = vP + kbase + (size_t)(kv0 + r1) * 64 + lc1;

  bf16x8 ones;
#pragma unroll
  for (int i = 0; i < 8; ++i) ones[i] = (bf16)1.0f;

  f32x4 o[2][4] = {};
  float lrow[2][4] = {};

#define STAGE(Ks_, Vs_)                   \
  do {                                    \
    gload_lds16(pK0, Ks_ + c0i * 8);      \
    gload_lds16(pK1, Ks_ + c1i * 8);      \
    gload_lds16(pV0, Vs_ + c0i * 8);      \
    gload_lds16(pV1, Vs_ + c1i * 8);      \
    pK0 += 64 * HD; pK1 += 64 * HD;       \
    pV0 += 64 * 64; pV1 += 64 * 64;       \
  } while (0)

  auto compute = [&](const bf16* Ks, const bf16* Vs) {
    f32x4 sa[2][4] = {};
    __builtin_amdgcn_s_setprio(1);
#pragma unroll
    for (int j = 0; j < 4; ++j) {
      int row = j * 16 + lr;
      int c0 = (lk ^ (row & 7)) * 8;
      int c1 = ((4 + lk) ^ (row & 7)) * 8;
      const bf16* kr = Ks + row * 64;
      bf16x8 b0 = *(const bf16x8*)(kr + c0);
      bf16x8 b1 = *(const bf16x8*)(kr + c1);
#pragma unroll
      for (int g = 0; g < 2; ++g) {
        sa[g][j] = mfma16(b0, aqh[g][0], sa[g][j]);  // A=K, B=Q (swapped)
        sa[g][j] = mfma16(b1, aqh[g][1], sa[g][j]);
        sa[g][j] = mfma16(b0, aql[g][0], sa[g][j]);
        sa[g][j] = mfma16(b1, aql[g][1], sa[g][j]);
      }
    }
    __builtin_amdgcn_s_setprio(0);

    // P = 2^sa directly (no max subtraction), pi-permuted A-fragments
    bf16x8 pa[2][2];
#pragma unroll
    for (int g = 0; g < 2; ++g)
#pragma unroll
      for (int jj = 0; jj < 2; ++jj)
#pragma unroll
        for (int r = 0; r < 4; ++r) {
          pa[g][0][jj * 4 + r] = (bf16)exp2_hw(sa[g][jj][r]);
          pa[g][1][jj * 4 + r] = (bf16)exp2_hw(sa[g][2 + jj][r]);
        }

    __builtin_amdgcn_s_setprio(1);
    f32x4 ls[2] = {};
#pragma unroll
    for (int g = 0; g < 2; ++g) {
      ls[g] = mfma16(pa[g][0], ones, ls[g]);  // rowsum(P) in o-layout
      ls[g] = mfma16(pa[g][1], ones, ls[g]);
    }
#pragma unroll
    for (int dj = 0; dj < 4; ++dj) {
      int row = dj * 16 + lr;
      const bf16* vr = Vs + row * 64;
#pragma unroll
      for (int p = 0; p < 2; ++p) {
        bf16x8 vf = *(const bf16x8*)(vr + (((p * 4 + lk) ^ (row & 7)) * 8));
#pragma unroll
        for (int g = 0; g < 2; ++g)
          o[g][dj] = mfma16(pa[g][p], vf, o[g][dj]);
      }
    }
    __builtin_amdgcn_s_setprio(0);
#pragma unroll
    for (int g = 0; g < 2; ++g)
#pragma unroll
      for (int r = 0; r < 4; ++r) lrow[g][r] += ls[g][r];
  };

  // prologue: stage tile 0 into A; barrier drains vmcnt
  STAGE(KsA, VsA);
  __syncthreads();

  for (int it = 0; it < SEQ / 128; it += 2) {   // 16 tiles per group
    STAGE(KsB, VsB);         // prefetch tile it+1 (overlaps compute below)
    compute(KsA, VsA);       // tile it
    __syncthreads();
    if (it + 2 < SEQ / 128) {
      STAGE(KsA, VsA);       // prefetch tile it+2
    }
    compute(KsB, VsB);       // tile it+1
    __syncthreads();
  }
#undef STAGE

  // ---- cross-group combine through LDS (pure f32 addition; loop's final
  // barrier guarantees all tile reads are done, so smem is reusable) ----
  float* xb = (float*)smem;                 // [256][41] f32, ~42 KB
  if (G == 1) {
    float* p = xb + gtid * 41;
#pragma unroll
    for (int g = 0; g < 2; ++g)
#pragma unroll
      for (int dj = 0; dj < 4; ++dj)
#pragma unroll
        for (int i = 0; i < 4; ++i)
          p[(g * 4 + dj) * 4 + i] = o[g][dj][i];
#pragma unroll
    for (int g = 0; g < 2; ++g)
#pragma unroll
      for (int r = 0; r < 4; ++r)
        p[32 + g * 4 + r] = lrow[g][r];
  }
  __syncthreads();
  if (G == 0) {
    float* p = xb + gtid * 41;
#pragma unroll
    for (int g = 0; g < 2; ++g)
#pragma unroll
      for (int dj = 0; dj < 4; ++dj)
#pragma unroll
        for (int i = 0; i < 4; ++i)
          o[g][dj][i] += p[(g * 4 + dj) * 4 + i];
#pragma unroll
    for (int g = 0; g < 2; ++g)
#pragma unroll
      for (int r = 0; r < 4; ++r)
        lrow[g][r] += p[32 + g * 4 + r];

    const int b = n >> 4, h = n & 15;
#pragma unroll
    for (int g = 0; g < 2; ++g)
#pragma unroll
      for (int r = 0; r < 4; ++r) {
        float inv = 1.0f / lrow[g][r];
        int s = q0 + g * 16 + lk * 4 + r;
        size_t base = ((size_t)(b * SEQ + s)) * DIM + h * HD;
#pragma unroll
        for (int j = 0; j < 4; ++j)
          aout[base + j * 16 + lr] = (bf16)(o[g][j][r] * inv);
      }
  }
}

extern "C" void kernel_launch(void* const* d_in, const int* in_sizes, int n_in,
                              void* d_out, int out_size, void* d_ws, size_t ws_size,
                              hipStream_t stream) {
  const float* x     = (const float*)d_in[0];
  const float* kqv_w = (const float*)d_in[1];
  const float* kqv_b = (const float*)d_in[2];
  const float* out_w = (const float*)d_in[3];
  const float* out_b = (const float*)d_in[4];
  float* out = (float*)d_out;

  const size_t NX  = (size_t)TOK * DIM;       // 4M elems
  const size_t NW  = (size_t)3 * DIM * DIM;   // 3M elems
  const size_t NO  = (size_t)DIM * DIM;       // 1M elems
  const size_t NKV = (size_t)BH * SEQ * HD;   // 4M elems

  bf16* xh   = (bf16*)d_ws;          // NX   (reused as aout after gemm_qkv)
  bf16* xl   = xh + NX;              // NX
  bf16* wbf  = xl + NX;              // NW
  bf16* wout = wbf + NW;             // NO
  bf16* qhh  = wout + NO;            // NKV
  bf16* qhl  = qhh + NKV;            // NKV
  bf16* kh   = qhl + NKV;            // NKV
  bf16* vP   = kh + NKV;             // NKV   (total 28M elems = 56 MB)
  bf16* aout = xh;

  const int PREP_BLOCKS = (int)((NX + NW + NO) / 8 / 256);  // 4096
  prep_kernel<<<PREP_BLOCKS, 256, 0, stream>>>(x, kqv_w, out_w, xh, xl, wbf, wout);
  gemm_qkv_ps<<<768, 256, 0, stream>>>(xh, xl, wbf, kqv_b, qhh, qhl, kh, vP);
  attn_kernel<<<512, 512, 0, stream>>>(qhh, qhl, kh, vP, aout);
  gemm_out<<<256, 256, 0, stream>>>(aout, wout, out_b, out);
}

// Round 18
// 129.126 us; speedup vs baseline: 1.0370x; 1.0370x over previous
//
#include <hip/hip_runtime.h>

#define SEQ   2048
#define DIM   1024
#define NH    16
#define HD    64
#define BH    32          // BATCH*NH
#define TOK   4096        // BATCH*SEQ

typedef __bf16 bf16;
typedef __attribute__((ext_vector_type(4))) __bf16 bf16x4;
typedef __attribute__((ext_vector_type(8))) __bf16 bf16x8;
typedef __attribute__((ext_vector_type(4))) float f32x4;

#define LOG2E 1.44269504f

__device__ inline f32x4 mfma16(bf16x8 a, bf16x8 b, f32x4 c) {
  return __builtin_amdgcn_mfma_f32_16x16x32_bf16(a, b, c, 0, 0, 0);
}

__device__ inline void gload_lds16(const bf16* g, bf16* lds) {
  __builtin_amdgcn_global_load_lds(
      (const __attribute__((address_space(1))) void*)g,
      (__attribute__((address_space(3))) void*)lds, 16, 0, 0);
}

__device__ inline float exp2_hw(float x) {  // v_exp_f32: D = 2^S0
  float r;
  asm("v_exp_f32 %0, %1" : "=v"(r) : "v"(x));
  return r;
}

// split 8 consecutive f32 into bf16 hi + lo vectors
__device__ inline void split8(const float* src, bf16x8& hi, bf16x8& lo) {
  float4 a = *(const float4*)src;
  float4 b = *(const float4*)(src + 4);
  float f[8] = {a.x, a.y, a.z, a.w, b.x, b.y, b.z, b.w};
#pragma unroll
  for (int i = 0; i < 8; ++i) {
    bf16 h = (bf16)f[i];
    hi[i] = h;
    lo[i] = (bf16)(f[i] - (float)h);
  }
}

__device__ inline void cast8(const float* src, bf16* dst) {
  float4 a = *(const float4*)src;
  float4 b = *(const float4*)(src + 4);
  bf16x8 v;
  v[0] = (bf16)a.x; v[1] = (bf16)a.y; v[2] = (bf16)a.z; v[3] = (bf16)a.w;
  v[4] = (bf16)b.x; v[5] = (bf16)b.y; v[6] = (bf16)b.z; v[7] = (bf16)b.w;
  *(bf16x8*)dst = v;
}

// ---------------- fused prologue: x hi/lo split + w_qkv cast + out_w cast.
__global__ void prep_kernel(const float* __restrict__ x,
                            const float* __restrict__ kqv_w,
                            const float* __restrict__ out_w,
                            bf16* __restrict__ xh, bf16* __restrict__ xl,
                            bf16* __restrict__ wbf, bf16* __restrict__ wout) {
  const int NX8 = TOK * DIM / 8;
  const int NW8 = 3 * DIM * DIM / 8;
  const int NO8 = DIM * DIM / 8;
  int i = blockIdx.x * 256 + threadIdx.x;
  if (i < NX8) {
    bf16x8 h, l;
    split8(x + (size_t)i * 8, h, l);
    ((bf16x8*)xh)[i] = h;
    ((bf16x8*)xl)[i] = l;
  } else if (i < NX8 + NW8) {
    int j = i - NX8;
    cast8(kqv_w + (size_t)j * 8, wbf + (size_t)j * 8);
  } else if (i < NX8 + NW8 + NO8) {
    int j = i - NX8 - NW8;
    cast8(out_w + (size_t)j * 8, wout + (size_t)j * 8);
  }
}

// ---------------- QKV GEMM: xh * wh^T (+ xl * wh^T for Q panels only) + bias.
// 2-phase prefetch dbuf; XCD-swizzled 1D grid. xl staged via LDS (per-lane
// fragment loads from global are uncoalesced — R17 lesson). V stored
// PRE-PERMUTED (vP): vP[n][kt][d][u], u = (p*4+l)*8 + h*4 + r  (kt = s>>6).
__global__ __launch_bounds__(256) void gemm_qkv_ps(
    const bf16* __restrict__ xh, const bf16* __restrict__ xl,
    const bf16* __restrict__ wbf, const float* __restrict__ bias,
    bf16* __restrict__ qhh, bf16* __restrict__ qhl, bf16* __restrict__ kh,
    bf16* __restrict__ vP) {
  __shared__ bf16 AhA[64 * 64], AlA[64 * 64], BhA[64 * 64];  // 24 KB
  __shared__ bf16 AhB[64 * 64], AlB[64 * 64], BhB[64 * 64];  // 24 KB
  const int tid = threadIdx.x;
  const int lane = tid & 63;
  const int wave = tid >> 6;
  const int lr = lane & 15, lk = lane >> 4;
  const int bid = blockIdx.x;
  const int swz = (bid & 7) * 96 + (bid >> 3);
  const int m0 = (swz / 24) * 128, n0 = (swz % 24) * 128;
  const bool two_term = (n0 < DIM);  // Q panels only: xl correction
  const int wm = (wave >> 1) * 64, wn = (wave & 1) * 64;
  f32x4 acc[4][4] = {};

  const int c0i = tid, c1i = 256 + tid;
  const int rp0 = c0i >> 3, lc0 = (c0i & 7) ^ (rp0 & 7);
  const int mm0 = (lc0 >> 2) * 64 + rp0, kk0 = (lc0 & 3) * 8;
  const int rp1 = c1i >> 3, lc1 = (c1i & 7) ^ (rp1 & 7);
  const int mm1 = (lc1 >> 2) * 64 + rp1, kk1 = (lc1 & 3) * 8;
  const bf16* pA0 = xh + (size_t)(m0 + mm0) * DIM + kk0;
  const bf16* pA1 = xh + (size_t)(m0 + mm1) * DIM + kk1;
  const bf16* pL0 = xl + (size_t)(m0 + mm0) * DIM + kk0;
  const bf16* pL1 = xl + (size_t)(m0 + mm1) * DIM + kk1;
  const bf16* pB0 = wbf + (size_t)(n0 + mm0) * DIM + kk0;
  const bf16* pB1 = wbf + (size_t)(n0 + mm1) * DIM + kk1;

  auto stageG = [&](bf16* Ah_, bf16* Al_, bf16* Bh_) {
    gload_lds16(pA0, Ah_ + c0i * 8);
    gload_lds16(pA1, Ah_ + c1i * 8);
    if (two_term) {
      gload_lds16(pL0, Al_ + c0i * 8);
      gload_lds16(pL1, Al_ + c1i * 8);
    }
    gload_lds16(pB0, Bh_ + c0i * 8);
    gload_lds16(pB1, Bh_ + c1i * 8);
    pA0 += 32; pA1 += 32; pL0 += 32; pL1 += 32;
    pB0 += 32; pB1 += 32;
  };

  auto computeG = [&](const bf16* Ah, const bf16* Al, const bf16* Bh) {
    bf16x8 afh[4], afl[4], bfv[4];
#pragma unroll
    for (int i = 0; i < 4; ++i) {
      int m = wm + i * 16 + lr;
      int rp = m & 63;
      int pc = ((m >> 6) * 4 + lk) ^ (rp & 7);
      afh[i] = *(const bf16x8*)(Ah + rp * 64 + pc * 8);
    }
#pragma unroll
    for (int j = 0; j < 4; ++j) {
      int m = wn + j * 16 + lr;
      int rp = m & 63;
      int pc = ((m >> 6) * 4 + lk) ^ (rp & 7);
      bfv[j] = *(const bf16x8*)(Bh + rp * 64 + pc * 8);
    }
    __builtin_amdgcn_s_setprio(1);
#pragma unroll
    for (int i = 0; i < 4; ++i)
#pragma unroll
      for (int j = 0; j < 4; ++j)
        acc[i][j] = mfma16(afh[i], bfv[j], acc[i][j]);
    __builtin_amdgcn_s_setprio(0);
    if (two_term) {
#pragma unroll
      for (int i = 0; i < 4; ++i) {
        int m = wm + i * 16 + lr;
        int rp = m & 63;
        int pc = ((m >> 6) * 4 + lk) ^ (rp & 7);
        afl[i] = *(const bf16x8*)(Al + rp * 64 + pc * 8);
      }
      __builtin_amdgcn_s_setprio(1);
#pragma unroll
      for (int i = 0; i < 4; ++i)
#pragma unroll
        for (int j = 0; j < 4; ++j)
          acc[i][j] = mfma16(afl[i], bfv[j], acc[i][j]);
      __builtin_amdgcn_s_setprio(0);
    }
  };

  stageG(AhA, AlA, BhA);  // K-step 0
  __syncthreads();
  for (int k0 = 0; k0 < DIM; k0 += 64) {
    stageG(AhB, AlB, BhB);           // prefetch step t+1
    computeG(AhA, AlA, BhA);         // step t
    __syncthreads();
    if (k0 + 64 < DIM) {
      stageG(AhA, AlA, BhA);         // prefetch step t+2
    }
    computeG(AhB, AlB, BhB);         // step t+1
    __syncthreads();
  }

  // D frag: row = lk*4 + r, col = lr
#pragma unroll
  for (int j = 0; j < 4; ++j) {
    int col = n0 + wn + j * 16 + lr;
    float bv = bias[col];
    int part = col >> 10, cc2 = col & 1023;
    int h = cc2 >> 6, d = cc2 & 63;
#pragma unroll
    for (int i = 0; i < 4; ++i) {
      int rowb = m0 + wm + i * 16 + lk * 4;
#pragma unroll
      for (int r = 0; r < 4; ++r) {
        int row = rowb + r;
        float val = acc[i][j][r] + bv;
        int b = row >> 11, s = row & 2047;
        int n = b * NH + h;
        size_t idx = ((size_t)n * SEQ + s) * HD + d;
        if (part == 0) {
          float vq = val * LOG2E;      // log2-domain fold
          bf16 qh_ = (bf16)vq;
          qhh[idx] = qh_;
          qhl[idx] = (bf16)(vq - (float)qh_);
        } else if (part == 1) {
          kh[idx] = (bf16)val;
        } else {
          // pre-permuted V: k = s -> (kt, p, hh, l, rr); u = (p*4+l)*8 + hh*4 + rr
          int kt = s >> 6;
          int s6 = s & 63;
          int p = (s6 >> 5) & 1;
          int s5 = s6 & 31;
          int hh = s5 >> 4, l = (s5 >> 2) & 3, rr = s5 & 3;
          int u = (p * 4 + l) * 8 + hh * 4 + rr;
          vP[(((size_t)n * 32 + kt) * 64 + d) * 64 + u] = (bf16)val;
        }
      }
    }
  }
}

// ---------------- output projection: C = A * Bw^T + bias, bf16 in, f32 out.
__global__ __launch_bounds__(256) void gemm_out(
    const bf16* __restrict__ A, const bf16* __restrict__ Bw,
    const float* __restrict__ bias, float* __restrict__ outF) {
  __shared__ bf16 AsA[64 * 64], BsA[64 * 64];
  __shared__ bf16 AsB[64 * 64], BsB[64 * 64];
  const int tid = threadIdx.x;
  const int lane = tid & 63;
  const int wave = tid >> 6;
  const int lr = lane & 15, lk = lane >> 4;
  const int bid = blockIdx.x;
  const int swz = (bid & 7) * 32 + (bid >> 3);
  const int m0 = (swz >> 3) * 128, n0 = (swz & 7) * 128;
  const int wm = (wave >> 1) * 64, wn = (wave & 1) * 64;
  f32x4 acc[4][4] = {};

  const int c0i = tid, c1i = 256 + tid;
  const int rp0 = c0i >> 3, lc0 = (c0i & 7) ^ (rp0 & 7);
  const int mm0 = (lc0 >> 2) * 64 + rp0, kk0 = (lc0 & 3) * 8;
  const int rp1 = c1i >> 3, lc1 = (c1i & 7) ^ (rp1 & 7);
  const int mm1 = (lc1 >> 2) * 64 + rp1, kk1 = (lc1 & 3) * 8;
  const bf16* pA0 = A + (size_t)(m0 + mm0) * DIM + kk0;
  const bf16* pA1 = A + (size_t)(m0 + mm1) * DIM + kk1;
  const bf16* pB0 = Bw + (size_t)(n0 + mm0) * DIM + kk0;
  const bf16* pB1 = Bw + (size_t)(n0 + mm1) * DIM + kk1;

#define STAGEO(As_, Bs_)              \
  do {                                \
    gload_lds16(pA0, As_ + c0i * 8);  \
    gload_lds16(pA1, As_ + c1i * 8);  \
    gload_lds16(pB0, Bs_ + c0i * 8);  \
    gload_lds16(pB1, Bs_ + c1i * 8);  \
    pA0 += 32; pA1 += 32;             \
    pB0 += 32; pB1 += 32;             \
  } while (0)

  auto computeO = [&](const bf16* As, const bf16* Bs) {
    bf16x8 af[4], bfv[4];
#pragma unroll
    for (int i = 0; i < 4; ++i) {
      int m = wm + i * 16 + lr;
      int rp = m & 63;
      int pc = ((m >> 6) * 4 + lk) ^ (rp & 7);
      af[i] = *(const bf16x8*)(As + rp * 64 + pc * 8);
    }
#pragma unroll
    for (int j = 0; j < 4; ++j) {
      int m = wn + j * 16 + lr;
      int rp = m & 63;
      int pc = ((m >> 6) * 4 + lk) ^ (rp & 7);
      bfv[j] = *(const bf16x8*)(Bs + rp * 64 + pc * 8);
    }
    __builtin_amdgcn_s_setprio(1);
#pragma unroll
    for (int i = 0; i < 4; ++i)
#pragma unroll
      for (int j = 0; j < 4; ++j)
        acc[i][j] = mfma16(af[i], bfv[j], acc[i][j]);
    __builtin_amdgcn_s_setprio(0);
  };

  STAGEO(AsA, BsA);
  __syncthreads();
  for (int k0 = 0; k0 < DIM; k0 += 64) {
    STAGEO(AsB, BsB);
    computeO(AsA, BsA);
    __syncthreads();
    if (k0 + 64 < DIM) {
      STAGEO(AsA, BsA);
    }
    computeO(AsB, BsB);
    __syncthreads();
  }
#undef STAGEO

#pragma unroll
  for (int j = 0; j < 4; ++j) {
    int col = n0 + wn + j * 16 + lr;
    float bv = bias[col];
#pragma unroll
    for (int i = 0; i < 4; ++i) {
      int rowb = m0 + wm + i * 16 + lk * 4;
#pragma unroll
      for (int r = 0; r < 4; ++r)
        outF[(size_t)(rowb + r) * DIM + col] = acc[i][j][r] + bv;
    }
  }
}

// ---------------- flash attention: intra-block KV-split (8 waves = 2 groups of
// 4), 32 q-rows/wave, swapped QK^T, in-register P, no max tracking. Group G
// processes KV-half G (16 tiles); since P = 2^s with no max, partials combine
// by pure f32 ADDITION through LDS at block end. 16 waves/CU.
__global__ __launch_bounds__(512) void attn_kernel(
    const bf16* __restrict__ qhh, const bf16* __restrict__ qhl,
    const bf16* __restrict__ kh, const bf16* __restrict__ vP,
    bf16* __restrict__ aout) {
  __shared__ bf16 smem[8 * 4096];  // 8 tiles x 8 KB = 64 KB; reused for combine
  const int tid = threadIdx.x;
  const int lane = tid & 63;
  const int w = tid >> 6;          // 0..7
  const int G = w >> 2;            // KV half
  const int wsub = w & 3;
  const int lr = lane & 15, lk = lane >> 4;
  const int bid = blockIdx.x;
  const int swz = (bid & 7) * 64 + (bid >> 3);
  const int n = swz >> 4;                        // head index
  const int q0 = (swz & 15) * 128 + wsub * 32;   // 32 q-rows per wave
  const int kv0 = G * (SEQ / 2);                 // this group's KV base

  // tile pointers: [buf A/B][group][K/V], 4096 elems (8 KB) each
  bf16* KsA = smem + ((0 * 2 + G) * 2 + 0) * 4096;
  bf16* VsA = smem + ((0 * 2 + G) * 2 + 1) * 4096;
  bf16* KsB = smem + ((1 * 2 + G) * 2 + 0) * 4096;
  bf16* VsB = smem + ((1 * 2 + G) * 2 + 1) * 4096;

  const bf16* qbh = qhh + ((size_t)n * SEQ + q0) * HD;
  const bf16* qbl = qhl + ((size_t)n * SEQ + q0) * HD;
  bf16x8 aqh[2][2], aql[2][2];
#pragma unroll
  for (int g = 0; g < 2; ++g) {
    aqh[g][0] = *(const bf16x8*)(qbh + (g * 16 + lr) * HD + lk * 8);
    aqh[g][1] = *(const bf16x8*)(qbh + (g * 16 + lr) * HD + 32 + lk * 8);
    aql[g][0] = *(const bf16x8*)(qbl + (g * 16 + lr) * HD + lk * 8);
    aql[g][1] = *(const bf16x8*)(qbl + (g * 16 + lr) * HD + 32 + lk * 8);
  }

  // staging: group-local thread gtid handles chunks gtid and 256+gtid;
  // chunk c -> LDS row rp=c>>3, logical chunk lc=(c&7)^(rp&7)  (both K and V)
  const int gtid = tid & 255;
  const int c0i = gtid, c1i = 256 + gtid;
  const int r0 = c0i >> 3, lc0 = ((c0i & 7) ^ (r0 & 7)) * 8;
  const int r1 = c1i >> 3, lc1 = ((c1i & 7) ^ (r1 & 7)) * 8;
  const size_t kbase = (size_t)n * SEQ * HD;
  const bf16* pK0 = kh + kbase + (size_t)(kv0 + r0) * HD + lc0;
  const bf16* pK1 = kh + kbase + (size_t)(kv0 + r1) * HD + lc1;
  const bf16* pV0 = vP + kbase + (size_t)(kv0 + r0) * 64 + lc0;  // vP tile: [64 d][64 u]
  const bf16* pV1 = vP + kbase + (size_t)(kv0 + r1) * 64 + lc1;

  bf16x8 ones;
#pragma unroll
  for (int i = 0; i < 8; ++i) ones[i] = (bf16)1.0f;

  f32x4 o[2][4] = {};
  float lrow[2][4] = {};

#define STAGE(Ks_, Vs_)                   \
  do {                                    \
    gload_lds16(pK0, Ks_ + c0i * 8);      \
    gload_lds16(pK1, Ks_ + c1i * 8);      \
    gload_lds16(pV0, Vs_ + c0i * 8);      \
    gload_lds16(pV1, Vs_ + c1i * 8);      \
    pK0 += 64 * HD; pK1 += 64 * HD;       \
    pV0 += 64 * 64; pV1 += 64 * 64;       \
  } while (0)

  auto compute = [&](const bf16* Ks, const bf16* Vs) {
    f32x4 sa[2][4] = {};
    __builtin_amdgcn_s_setprio(1);
#pragma unroll
    for (int j = 0; j < 4; ++j) {
      int row = j * 16 + lr;
      int c0 = (lk ^ (row & 7)) * 8;
      int c1 = ((4 + lk) ^ (row & 7)) * 8;
      const bf16* kr = Ks + row * 64;
      bf16x8 b0 = *(const bf16x8*)(kr + c0);
      bf16x8 b1 = *(const bf16x8*)(kr + c1);
#pragma unroll
      for (int g = 0; g < 2; ++g) {
        sa[g][j] = mfma16(b0, aqh[g][0], sa[g][j]);  // A=K, B=Q (swapped)
        sa[g][j] = mfma16(b1, aqh[g][1], sa[g][j]);
        sa[g][j] = mfma16(b0, aql[g][0], sa[g][j]);
        sa[g][j] = mfma16(b1, aql[g][1], sa[g][j]);
      }
    }
    __builtin_amdgcn_s_setprio(0);

    // P = 2^sa directly (no max subtraction), pi-permuted A-fragments
    bf16x8 pa[2][2];
#pragma unroll
    for (int g = 0; g < 2; ++g)
#pragma unroll
      for (int jj = 0; jj < 2; ++jj)
#pragma unroll
        for (int r = 0; r < 4; ++r) {
          pa[g][0][jj * 4 + r] = (bf16)exp2_hw(sa[g][jj][r]);
          pa[g][1][jj * 4 + r] = (bf16)exp2_hw(sa[g][2 + jj][r]);
        }

    __builtin_amdgcn_s_setprio(1);
    f32x4 ls[2] = {};
#pragma unroll
    for (int g = 0; g < 2; ++g) {
      ls[g] = mfma16(pa[g][0], ones, ls[g]);  // rowsum(P) in o-layout
      ls[g] = mfma16(pa[g][1], ones, ls[g]);
    }
#pragma unroll
    for (int dj = 0; dj < 4; ++dj) {
      int row = dj * 16 + lr;
      const bf16* vr = Vs + row * 64;
#pragma unroll
      for (int p = 0; p < 2; ++p) {
        bf16x8 vf = *(const bf16x8*)(vr + (((p * 4 + lk) ^ (row & 7)) * 8));
#pragma unroll
        for (int g = 0; g < 2; ++g)
          o[g][dj] = mfma16(pa[g][p], vf, o[g][dj]);
      }
    }
    __builtin_amdgcn_s_setprio(0);
#pragma unroll
    for (int g = 0; g < 2; ++g)
#pragma unroll
      for (int r = 0; r < 4; ++r) lrow[g][r] += ls[g][r];
  };

  // prologue: stage tile 0 into A; barrier drains vmcnt
  STAGE(KsA, VsA);
  __syncthreads();

  for (int it = 0; it < SEQ / 128; it += 2) {   // 16 tiles per group
    STAGE(KsB, VsB);         // prefetch tile it+1 (overlaps compute below)
    compute(KsA, VsA);       // tile it
    __syncthreads();
    if (it + 2 < SEQ / 128) {
      STAGE(KsA, VsA);       // prefetch tile it+2
    }
    compute(KsB, VsB);       // tile it+1
    __syncthreads();
  }
#undef STAGE

  // ---- cross-group combine through LDS (pure f32 addition; loop's final
  // barrier guarantees all tile reads are done, so smem is reusable) ----
  float* xb = (float*)smem;                 // [256][41] f32, ~42 KB
  if (G == 1) {
    float* p = xb + gtid * 41;
#pragma unroll
    for (int g = 0; g < 2; ++g)
#pragma unroll
      for (int dj = 0; dj < 4; ++dj)
#pragma unroll
        for (int i = 0; i < 4; ++i)
          p[(g * 4 + dj) * 4 + i] = o[g][dj][i];
#pragma unroll
    for (int g = 0; g < 2; ++g)
#pragma unroll
      for (int r = 0; r < 4; ++r)
        p[32 + g * 4 + r] = lrow[g][r];
  }
  __syncthreads();
  if (G == 0) {
    float* p = xb + gtid * 41;
#pragma unroll
    for (int g = 0; g < 2; ++g)
#pragma unroll
      for (int dj = 0; dj < 4; ++dj)
#pragma unroll
        for (int i = 0; i < 4; ++i)
          o[g][dj][i] += p[(g * 4 + dj) * 4 + i];
#pragma unroll
    for (int g = 0; g < 2; ++g)
#pragma unroll
      for (int r = 0; r < 4; ++r)
        lrow[g][r] += p[32 + g * 4 + r];

    const int b = n >> 4, h = n & 15;
#pragma unroll
    for (int g = 0; g < 2; ++g)
#pragma unroll
      for (int r = 0; r < 4; ++r) {
        float inv = 1.0f / lrow[g][r];
        int s = q0 + g * 16 + lk * 4 + r;
        size_t base = ((size_t)(b * SEQ + s)) * DIM + h * HD;
#pragma unroll
        for (int j = 0; j < 4; ++j)
          aout[base + j * 16 + lr] = (bf16)(o[g][j][r] * inv);
      }
  }
}

extern "C" void kernel_launch(void* const* d_in, const int* in_sizes, int n_in,
                              void* d_out, int out_size, void* d_ws, size_t ws_size,
                              hipStream_t stream) {
  const float* x     = (const float*)d_in[0];
  const float* kqv_w = (const float*)d_in[1];
  const float* kqv_b = (const float*)d_in[2];
  const float* out_w = (const float*)d_in[3];
  const float* out_b = (const float*)d_in[4];
  float* out = (float*)d_out;

  const size_t NX  = (size_t)TOK * DIM;       // 4M elems
  const size_t NW  = (size_t)3 * DIM * DIM;   // 3M elems
  const size_t NO  = (size_t)DIM * DIM;       // 1M elems
  const size_t NKV = (size_t)BH * SEQ * HD;   // 4M elems

  bf16* xh   = (bf16*)d_ws;          // NX   (reused as aout after gemm_qkv)
  bf16* xl   = xh + NX;              // NX
  bf16* wbf  = xl + NX;              // NW
  bf16* wout = wbf + NW;             // NO
  bf16* qhh  = wout + NO;            // NKV
  bf16* qhl  = qhh + NKV;            // NKV
  bf16* kh   = qhl + NKV;            // NKV
  bf16* vP   = kh + NKV;             // NKV   (total 28M elems = 56 MB)
  bf16* aout = xh;

  const int PREP_BLOCKS = (int)((NX + NW + NO) / 8 / 256);  // 4096
  prep_kernel<<<PREP_BLOCKS, 256, 0, stream>>>(x, kqv_w, out_w, xh, xl, wbf, wout);
  gemm_qkv_ps<<<768, 256, 0, stream>>>(xh, xl, wbf, kqv_b, qhh, qhl, kh, vP);
  attn_kernel<<<512, 512, 0, stream>>>(qhh, qhl, kh, vP, aout);
  gemm_out<<<256, 256, 0, stream>>>(aout, wout, out_b, out);
}